// Round 12
// baseline (24.078 us; speedup 1.0000x reference)
//
#include <hip/hip_runtime.h>

typedef float f2 __attribute__((ext_vector_type(2)));

#define FD 128          // feature dim
#define NB 1024         // batch
#define NC 16           // classes
#define NCB (NC * 16)   // 256 class blocks: 16 classes x (4x4 i,j chunks)
#define MAXM 112        // max supported class size (mean 64, sd ~7.7)
#define CKCAP 28        // ceil(MAXM/4) rows per chunk
#define LDP 132         // LDS row stride (floats): 16B-aligned, bank phase +4/row

// ONE kernel (R1-R11 fit: bench ~= 17us fixed + 4-5us/extra-node + work ->
// single node mandatory). Output partitioned write-disjointly:
//   class blocks (bid < NCB): class c = bid>>4, (qi,qj) chunk pair -> scores.
//   fill blocks  (bid >= NCB): row i = bid-NCB, zeros where labels differ.
// Member list built by deterministic ballot prefix-scan (identical in every
// block of a class) -> each (i,j) owned by exactly one block.
//
// R4: read W1 once per pass (broadcast column loads), don't stream per task.
// R6/R7: low bytes/FMA + multi-row register blocking; R5 layout is best.
// R10: guarded second k-loop REGRESSED (S=17..20 classes trigger it empty).
// R11: v_pk_fma_f32 packing WON (22.96 -> 21.99; full-rate confirmed).
// R12: micro - W1 as 2x dwordx4 (not 4x dwordx2) + ds_read_b64 f-reads
//   (2k grouping): 24 -> 20 instr/k. Convergence probe for the 17us floor.
__global__ __launch_bounds__(256) void eg_one(
    const float* __restrict__ f, const int* __restrict__ labels,
    const float* __restrict__ W1, const float* __restrict__ b1,
    const float* __restrict__ w2, const float* __restrict__ b2,
    float* __restrict__ out)
{
  const int bid = blockIdx.x;
  const int tid = threadIdx.x;

  if (bid >= NCB) {
    // ---------- fill path ----------
    const int i = bid - NCB;
    const int li = labels[i];
    float* __restrict__ row = out + (size_t)i * NB;
#pragma unroll
    for (int q = 0; q < 4; ++q) {
      const int j = tid + q * 256;
      if (labels[j] != li) row[j] = 0.f;   // masked elems must be exactly 0
    }
    return;
  }

  // ---------- class path ----------
  // lds union (barrier-separated lifetimes):
  //   phase 1: fs[2*CKCAP][LDP]  staged f rows (i-chunk then j-chunk)
  //   phase 2: his[CKCAP][LDP] | hjs[CKCAP][LDP]
  __shared__ __align__(16) float lds[2 * CKCAP * LDP];
  __shared__ int mem[MAXM];
  __shared__ int mcnt;
  float (*fs)[LDP]  = reinterpret_cast<float (*)[LDP]>(lds);
  float (*his)[LDP] = reinterpret_cast<float (*)[LDP]>(lds);
  float (*hjs)[LDP] = reinterpret_cast<float (*)[LDP]>(lds + CKCAP * LDP);

  const int c  = bid >> 4;
  const int qi = (bid >> 2) & 3;
  const int qj = bid & 3;

  // Deterministic member list (wave 0): ballot prefix over ascending j.
  if (tid < 64) {
    const int lane = tid;
    int base = 0;
    for (int w = 0; w < 16; ++w) {
      const int j = w * 64 + lane;
      const bool fl = (labels[j] == c);
      const unsigned long long msk = __ballot(fl);
      const int pos = base + __popcll(msk & ((1ull << lane) - 1ull));
      if (fl && pos < MAXM) mem[pos] = j;
      base += __popcll(msk);
    }
    if (lane == 0) mcnt = base < MAXM ? base : MAXM;
  }
  __syncthreads();

  const int m  = mcnt;
  const int ck = (m + 3) >> 2;                       // ceil(m/4) <= CKCAP
  const int i0 = qi * ck;
  const int SI = max(0, min(m, i0 + ck) - i0);
  const int j0 = qj * ck;
  const int SJ = max(0, min(m, j0 + ck) - j0);
  const int R  = SI + SJ;

  // Stage f rows of both chunks into LDS (coalesced float4).
  for (int idx = tid; idx < R * 32; idx += 256) {
    const int r  = idx >> 5;
    const int fo = (idx & 31) << 2;
    const int g  = (r < SI) ? mem[i0 + r] : mem[j0 + (r - SI)];
    *reinterpret_cast<float4*>(&fs[r][fo]) =
        *reinterpret_cast<const float4*>(f + g * FD + fo);
  }
  __syncthreads();

  // h-compute: thread = (half, r8, dg) -> rows {r8,r8+8,r8+16,r8+24} x 8 dims.
  // half 0 -> hi (b1 folded, W1[:D]); half 1 -> hj (W1[D:]).
  const int half  = tid >> 7;
  const int r8    = (tid >> 4) & 7;
  const int dg    = (tid & 15) << 3;
  const int S     = half ? SJ : SI;
  const int rbase = half ? SI : 0;

  f2 acc[4][4];
  {
    f2 b01 = {0.f, 0.f}, b23 = b01, b45 = b01, b67 = b01;
    if (!half) {
      const f2* bp = reinterpret_cast<const f2*>(b1 + dg);
      b01 = bp[0]; b23 = bp[1]; b45 = bp[2]; b67 = bp[3];
    }
#pragma unroll
    for (int rr = 0; rr < 4; ++rr) {
      acc[rr][0] = b01; acc[rr][1] = b23; acc[rr][2] = b45; acc[rr][3] = b67;
    }
  }
  const float* frow[4];
#pragma unroll
  for (int rr = 0; rr < 4; ++rr) {
    const int r = r8 + rr * 8;
    frow[rr] = fs[rbase + (r < S ? r : 0)];   // clamped rows discarded at write
  }
  const float* __restrict__ Wp = W1 + half * FD * FD + dg;

  // 2-k steps: W1 = 2x dwordx4 per k (bitcast to f2), f = 1x ds_read_b64 per
  // row per 2k. Same per-output accumulation order as R11 (k ascending).
#pragma unroll 4
  for (int k2 = 0; k2 < FD / 2; ++k2) {
    const int k = k2 << 1;
    const float4 wa0 = *reinterpret_cast<const float4*>(Wp + k * FD);
    const float4 wb0 = *reinterpret_cast<const float4*>(Wp + k * FD + 4);
    const float4 wa1 = *reinterpret_cast<const float4*>(Wp + (k + 1) * FD);
    const float4 wb1 = *reinterpret_cast<const float4*>(Wp + (k + 1) * FD + 4);
    const f2 w00 = {wa0.x, wa0.y}, w01 = {wa0.z, wa0.w};
    const f2 w02 = {wb0.x, wb0.y}, w03 = {wb0.z, wb0.w};
    const f2 w10 = {wa1.x, wa1.y}, w11 = {wa1.z, wa1.w};
    const f2 w12 = {wb1.x, wb1.y}, w13 = {wb1.z, wb1.w};
    f2 fp[4];
#pragma unroll
    for (int rr = 0; rr < 4; ++rr)
      fp[rr] = *reinterpret_cast<const f2*>(frow[rr] + k);   // ds_read_b64
#pragma unroll
    for (int rr = 0; rr < 4; ++rr) {
      const f2 f0 = {fp[rr].x, fp[rr].x};
      acc[rr][0] = __builtin_elementwise_fma(f0, w00, acc[rr][0]);
      acc[rr][1] = __builtin_elementwise_fma(f0, w01, acc[rr][1]);
      acc[rr][2] = __builtin_elementwise_fma(f0, w02, acc[rr][2]);
      acc[rr][3] = __builtin_elementwise_fma(f0, w03, acc[rr][3]);
    }
#pragma unroll
    for (int rr = 0; rr < 4; ++rr) {
      const f2 f1 = {fp[rr].y, fp[rr].y};
      acc[rr][0] = __builtin_elementwise_fma(f1, w10, acc[rr][0]);
      acc[rr][1] = __builtin_elementwise_fma(f1, w11, acc[rr][1]);
      acc[rr][2] = __builtin_elementwise_fma(f1, w12, acc[rr][2]);
      acc[rr][3] = __builtin_elementwise_fma(f1, w13, acc[rr][3]);
    }
  }
  __syncthreads();   // all fs reads complete before lds is reused as his/hjs

#pragma unroll
  for (int rr = 0; rr < 4; ++rr) {
    const int r = r8 + rr * 8;
    if (r < S) {
      float* dst = (half ? hjs[r] : his[r]) + dg;
      f2* d2 = reinterpret_cast<f2*>(dst);
      d2[0] = acc[rr][0]; d2[1] = acc[rr][1];
      d2[2] = acc[rr][2]; d2[3] = acc[rr][3];
    }
  }
  __syncthreads();

  // pairs: per wave an 8x8 (i,j) tile; lane owns one pair; float4 d-loop,
  // packed relu/fma. stride-132 rows spread across banks, conflict-free.
  const int wv = tid >> 6, lane = tid & 63;
  const int a = lane >> 3, b = lane & 7;
  const int nti = (SI + 7) >> 3, ntj = (SJ + 7) >> 3;
  const float bb = b2[0];
  const f2 z2 = {0.f, 0.f};
  for (int t = wv; t < nti * ntj; t += 4) {
    const int ti = t / ntj, tj = t - ti * ntj;
    const int ii = ti * 8 + a, jj = tj * 8 + b;
    const int ic = ii < SI ? ii : SI - 1;   // clamp: keep LDS reads in-bounds
    const int jc = jj < SJ ? jj : SJ - 1;
    f2 accp = z2;
#pragma unroll 8
    for (int d = 0; d < FD; d += 4) {
      const float4 hv = *reinterpret_cast<const float4*>(&his[ic][d]);
      const float4 gv = *reinterpret_cast<const float4*>(&hjs[jc][d]);
      const float4 w4 = *reinterpret_cast<const float4*>(&w2[d]);
      const f2 h01 = {hv.x, hv.y}, h23 = {hv.z, hv.w};
      const f2 g01 = {gv.x, gv.y}, g23 = {gv.z, gv.w};
      const f2 u01 = {w4.x, w4.y}, u23 = {w4.z, w4.w};
      accp = __builtin_elementwise_fma(
          __builtin_elementwise_max(h01 + g01, z2), u01, accp);
      accp = __builtin_elementwise_fma(
          __builtin_elementwise_max(h23 + g23, z2), u23, accp);
    }
    if (ii < SI && jj < SJ) {
      const int gi = mem[i0 + ii], gj = mem[j0 + jj];
      const float acc2 = accp.x + accp.y;
      out[(size_t)gi * NB + gj] =
          (gi == gj) ? 0.f : 1.f / (1.f + __expf(-(acc2 + bb)));
    }
  }
}

extern "C" void kernel_launch(void* const* d_in, const int* in_sizes, int n_in,
                              void* d_out, int out_size, void* d_ws, size_t ws_size,
                              hipStream_t stream) {
  const float* f      = (const float*)d_in[0];
  const int*   labels = (const int*)d_in[1];
  const float* W1     = (const float*)d_in[2];
  const float* b1     = (const float*)d_in[3];
  const float* w2     = (const float*)d_in[4];
  const float* b2     = (const float*)d_in[5];
  float* out = (float*)d_out;

  eg_one<<<NCB + NB, 256, 0, stream>>>(f, labels, W1, b1, w2, b2, out);
}

// Round 13
// 21.984 us; speedup vs baseline: 1.0952x; 1.0952x over previous
//
#include <hip/hip_runtime.h>

typedef float f2 __attribute__((ext_vector_type(2)));

#define FD 128          // feature dim
#define NB 1024         // batch
#define NC 16           // classes
#define NCB (NC * 16)   // 256 class blocks: 16 classes x (4x4 i,j chunks)
#define MAXM 112        // max supported class size (mean 64, sd ~7.7)
#define CKCAP 28        // ceil(MAXM/4) rows per chunk
#define LDP 132         // LDS row stride (floats): 16B-aligned, bank phase +4/row

// ONE kernel (R1-R12 fit: bench ~= 17us fixed + 4-5us/extra-node + work ->
// single node mandatory). Output partitioned write-disjointly:
//   class blocks (bid < NCB): class c = bid>>4, (qi,qj) chunk pair -> scores.
//   fill blocks  (bid >= NCB): row i = bid-NCB, zeros where labels differ.
// Member list built by deterministic ballot prefix-scan (identical in every
// block of a class) -> each (i,j) owned by exactly one block.
//
// R4: read W1 once per pass (broadcast column loads), don't stream per task.
// R6/R7: low bytes/FMA + multi-row register blocking; R5 layout is best.
// R10: guarded second k-loop REGRESSED (S=17..20 classes trigger it empty).
// R11: v_pk_fma_f32 packing WON (22.96 -> 21.99; full-rate confirmed). BEST.
// R12: 2-k grouping + ds_read_b64 REGRESSED (24.08; register-pressure /
//   scheduling second-order effects beat the instruction-count saving).
// R13: exact revert to R11 (the measured best).
__global__ __launch_bounds__(256) void eg_one(
    const float* __restrict__ f, const int* __restrict__ labels,
    const float* __restrict__ W1, const float* __restrict__ b1,
    const float* __restrict__ w2, const float* __restrict__ b2,
    float* __restrict__ out)
{
  const int bid = blockIdx.x;
  const int tid = threadIdx.x;

  if (bid >= NCB) {
    // ---------- fill path ----------
    const int i = bid - NCB;
    const int li = labels[i];
    float* __restrict__ row = out + (size_t)i * NB;
#pragma unroll
    for (int q = 0; q < 4; ++q) {
      const int j = tid + q * 256;
      if (labels[j] != li) row[j] = 0.f;   // masked elems must be exactly 0
    }
    return;
  }

  // ---------- class path ----------
  // lds union (barrier-separated lifetimes):
  //   phase 1: fs[2*CKCAP][LDP]  staged f rows (i-chunk then j-chunk)
  //   phase 2: his[CKCAP][LDP] | hjs[CKCAP][LDP]
  __shared__ __align__(16) float lds[2 * CKCAP * LDP];
  __shared__ int mem[MAXM];
  __shared__ int mcnt;
  float (*fs)[LDP]  = reinterpret_cast<float (*)[LDP]>(lds);
  float (*his)[LDP] = reinterpret_cast<float (*)[LDP]>(lds);
  float (*hjs)[LDP] = reinterpret_cast<float (*)[LDP]>(lds + CKCAP * LDP);

  const int c  = bid >> 4;
  const int qi = (bid >> 2) & 3;
  const int qj = bid & 3;

  // Deterministic member list (wave 0): ballot prefix over ascending j.
  if (tid < 64) {
    const int lane = tid;
    int base = 0;
    for (int w = 0; w < 16; ++w) {
      const int j = w * 64 + lane;
      const bool fl = (labels[j] == c);
      const unsigned long long msk = __ballot(fl);
      const int pos = base + __popcll(msk & ((1ull << lane) - 1ull));
      if (fl && pos < MAXM) mem[pos] = j;
      base += __popcll(msk);
    }
    if (lane == 0) mcnt = base < MAXM ? base : MAXM;
  }
  __syncthreads();

  const int m  = mcnt;
  const int ck = (m + 3) >> 2;                       // ceil(m/4) <= CKCAP
  const int i0 = qi * ck;
  const int SI = max(0, min(m, i0 + ck) - i0);
  const int j0 = qj * ck;
  const int SJ = max(0, min(m, j0 + ck) - j0);
  const int R  = SI + SJ;

  // Stage f rows of both chunks into LDS (coalesced float4).
  for (int idx = tid; idx < R * 32; idx += 256) {
    const int r  = idx >> 5;
    const int fo = (idx & 31) << 2;
    const int g  = (r < SI) ? mem[i0 + r] : mem[j0 + (r - SI)];
    *reinterpret_cast<float4*>(&fs[r][fo]) =
        *reinterpret_cast<const float4*>(f + g * FD + fo);
  }
  __syncthreads();

  // h-compute: thread = (half, r8, dg) -> rows {r8,r8+8,r8+16,r8+24} x 8 dims.
  // half 0 -> hi (b1 folded, W1[:D]); half 1 -> hj (W1[D:]).
  const int half  = tid >> 7;
  const int r8    = (tid >> 4) & 7;
  const int dg    = (tid & 15) << 3;
  const int S     = half ? SJ : SI;
  const int rbase = half ? SI : 0;

  f2 acc[4][4];
  {
    f2 b01 = {0.f, 0.f}, b23 = b01, b45 = b01, b67 = b01;
    if (!half) {
      const f2* bp = reinterpret_cast<const f2*>(b1 + dg);
      b01 = bp[0]; b23 = bp[1]; b45 = bp[2]; b67 = bp[3];
    }
#pragma unroll
    for (int rr = 0; rr < 4; ++rr) {
      acc[rr][0] = b01; acc[rr][1] = b23; acc[rr][2] = b45; acc[rr][3] = b67;
    }
  }
  const float* frow[4];
#pragma unroll
  for (int rr = 0; rr < 4; ++rr) {
    const int r = r8 + rr * 8;
    frow[rr] = fs[rbase + (r < S ? r : 0)];   // clamped rows discarded at write
  }
  const float* __restrict__ Wp = W1 + half * FD * FD + dg;
#pragma unroll 4
  for (int k = 0; k < FD; ++k) {
    const f2* wp = reinterpret_cast<const f2*>(Wp + k * FD);  // 8 floats = 2x16B loads
    const f2 wv0 = wp[0], wv1 = wp[1], wv2 = wp[2], wv3 = wp[3];
#pragma unroll
    for (int rr = 0; rr < 4; ++rr) {
      const float fv = frow[rr][k];
      const f2 fvv = {fv, fv};
      acc[rr][0] = __builtin_elementwise_fma(fvv, wv0, acc[rr][0]);
      acc[rr][1] = __builtin_elementwise_fma(fvv, wv1, acc[rr][1]);
      acc[rr][2] = __builtin_elementwise_fma(fvv, wv2, acc[rr][2]);
      acc[rr][3] = __builtin_elementwise_fma(fvv, wv3, acc[rr][3]);
    }
  }
  __syncthreads();   // all fs reads complete before lds is reused as his/hjs

#pragma unroll
  for (int rr = 0; rr < 4; ++rr) {
    const int r = r8 + rr * 8;
    if (r < S) {
      float* dst = (half ? hjs[r] : his[r]) + dg;
      f2* d2 = reinterpret_cast<f2*>(dst);
      d2[0] = acc[rr][0]; d2[1] = acc[rr][1];
      d2[2] = acc[rr][2]; d2[3] = acc[rr][3];
    }
  }
  __syncthreads();

  // pairs: per wave an 8x8 (i,j) tile; lane owns one pair; float4 d-loop,
  // packed relu/fma. stride-132 rows spread across banks, conflict-free.
  const int wv = tid >> 6, lane = tid & 63;
  const int a = lane >> 3, b = lane & 7;
  const int nti = (SI + 7) >> 3, ntj = (SJ + 7) >> 3;
  const float bb = b2[0];
  const f2 z2 = {0.f, 0.f};
  for (int t = wv; t < nti * ntj; t += 4) {
    const int ti = t / ntj, tj = t - ti * ntj;
    const int ii = ti * 8 + a, jj = tj * 8 + b;
    const int ic = ii < SI ? ii : SI - 1;   // clamp: keep LDS reads in-bounds
    const int jc = jj < SJ ? jj : SJ - 1;
    f2 accp = z2;
#pragma unroll 8
    for (int d = 0; d < FD; d += 4) {
      const float4 hv = *reinterpret_cast<const float4*>(&his[ic][d]);
      const float4 gv = *reinterpret_cast<const float4*>(&hjs[jc][d]);
      const float4 w4 = *reinterpret_cast<const float4*>(&w2[d]);
      const f2 h01 = {hv.x, hv.y}, h23 = {hv.z, hv.w};
      const f2 g01 = {gv.x, gv.y}, g23 = {gv.z, gv.w};
      const f2 u01 = {w4.x, w4.y}, u23 = {w4.z, w4.w};
      accp = __builtin_elementwise_fma(
          __builtin_elementwise_max(h01 + g01, z2), u01, accp);
      accp = __builtin_elementwise_fma(
          __builtin_elementwise_max(h23 + g23, z2), u23, accp);
    }
    if (ii < SI && jj < SJ) {
      const int gi = mem[i0 + ii], gj = mem[j0 + jj];
      const float acc2 = accp.x + accp.y;
      out[(size_t)gi * NB + gj] =
          (gi == gj) ? 0.f : 1.f / (1.f + __expf(-(acc2 + bb)));
    }
  }
}

extern "C" void kernel_launch(void* const* d_in, const int* in_sizes, int n_in,
                              void* d_out, int out_size, void* d_ws, size_t ws_size,
                              hipStream_t stream) {
  const float* f      = (const float*)d_in[0];
  const int*   labels = (const int*)d_in[1];
  const float* W1     = (const float*)d_in[2];
  const float* b1     = (const float*)d_in[3];
  const float* w2     = (const float*)d_in[4];
  const float* b2     = (const float*)d_in[5];
  float* out = (float*)d_out;

  eg_one<<<NCB + NB, 256, 0, stream>>>(f, labels, W1, b1, w2, b2, out);
}